// Round 8
// baseline (130.270 us; speedup 1.0000x reference)
//
#include <hip/hip_runtime.h>

// B=2, H=16, S=2048, DK=DV=64; out flat = [B,H,S,DV] flat (raw reshape).
#define S_LEN 2048
#define DHEAD 64
#define BHEADS 32
#define NTILES 32                       // key tiles of 64
#define HEAD_ELEMS (S_LEN * DHEAD)
#define TENS_ELEMS (BHEADS * HEAD_ELEMS)
#define TILE_HALVES 4096                // 8 KB per (bh,tile) fragment block

typedef _Float16 half8_t __attribute__((ext_vector_type(8)));
typedef _Float16 half4_t __attribute__((ext_vector_type(4)));
typedef _Float16 half2_t __attribute__((ext_vector_type(2)));
typedef float float4_t __attribute__((ext_vector_type(4)));

// 1/sqrt(64) * log2(e), folded into K so scores land in exp2 domain
#define SC_LOG2E 0.18033688011112042f

// Fragment-linear layouts (16 B per lane per fragment):
//  Kf[bh][t][f=mt*2+kh][lane] : K[t*64 + mt*16 + (lane&15)][kh*32 + (lane>>4)*8 + j] * SC
//  Vf[bh][t][fv=vt*2+c][lane][j] : V[t*64 + c*32 + (j>>2)*16 + (lane>>4)*4 + (j&3)]
//                                   [vt*16 + (lane&15)]
// Key fact (R9): Vf's k-ordering equals the k-ordering of a P^T B-operand
// built by concatenating QK sub-tile outputs 2c (regs 0-3) and 2c+1 (regs
// 4-7), so PV can use mfma_f32_16x16x32_f16 directly — half the PV MFMAs.

// direct-to-LDS DMA: 64 lanes x 16 B, per-lane global src, wave-uniform LDS
// dest (HW adds lane*16 to the dest base)
typedef const __attribute__((address_space(1))) unsigned int gas_u32;
typedef __attribute__((address_space(3))) unsigned int las_u32;
__device__ __forceinline__ void stage16(const void* g, void* l) {
    __builtin_amdgcn_global_load_lds((gas_u32*)g, (las_u32*)l, 16, 0, 0);
}

// ---------------- prepass: build fragment-ordered K/VT ----------------
__global__ __launch_bounds__(256) void prep_kernel(const float* __restrict__ K,
                                                   const float* __restrict__ V,
                                                   _Float16* __restrict__ Kf,
                                                   _Float16* __restrict__ Vf) {
    __shared__ _Float16 tile[64][72];   // V tile [s][v], padded
    const int bh = blockIdx.x >> 5;
    const int t = blockIdx.x & 31;
    const int tid = threadIdx.x;

    const float* Ksrc = K + (bh * S_LEN + t * 64) * DHEAD;
    const float4* vs = (const float4*)(V + (bh * S_LEN + t * 64) * DHEAD);
#pragma unroll
    for (int it = 0; it < 4; ++it) {
        int i = it * 256 + tid;                 // 1024 float4 = 64x64 floats
        float4 vv = vs[i];
        int r = i >> 4, c4 = (i & 15) * 4;
        half4_t hv = {(_Float16)vv.x, (_Float16)vv.y, (_Float16)vv.z, (_Float16)vv.w};
        *(half4_t*)&tile[r][c4] = hv;
    }

    // K fragments: pure permutation of the fp32 tile, no LDS needed
    _Float16* kd = Kf + (bh * NTILES + t) * TILE_HALVES;
#pragma unroll
    for (int it = 0; it < 2; ++it) {
        int c = it * 256 + tid;                 // 512 chunks of 16 B
        int f = c >> 6, lane = c & 63;
        int row = (f >> 1) * 16 + (lane & 15);
        int d0 = (f & 1) * 32 + (lane >> 4) * 8;
        const float4* s = (const float4*)(Ksrc + row * DHEAD + d0);
        float4 a = s[0], b = s[1];
        half8_t h = {(_Float16)(a.x * SC_LOG2E), (_Float16)(a.y * SC_LOG2E),
                     (_Float16)(a.z * SC_LOG2E), (_Float16)(a.w * SC_LOG2E),
                     (_Float16)(b.x * SC_LOG2E), (_Float16)(b.y * SC_LOG2E),
                     (_Float16)(b.z * SC_LOG2E), (_Float16)(b.w * SC_LOG2E)};
        *(half8_t*)(kd + c * 8) = h;
    }
    __syncthreads();

    // VT fragments: transpose gather from LDS
    _Float16* vd = Vf + (bh * NTILES + t) * TILE_HALVES;
#pragma unroll
    for (int it = 0; it < 2; ++it) {
        int c = it * 256 + tid;
        int fv = c >> 6, lane = c & 63;
        int vt = fv >> 1, ktp = fv & 1;
        int v = vt * 16 + (lane & 15);
        int g = lane >> 4;
        half8_t h;
#pragma unroll
        for (int j = 0; j < 8; ++j) {
            int key = ktp * 32 + (j >> 2) * 16 + g * 4 + (j & 3);
            h[j] = tile[key][v];
        }
        *(half8_t*)(vd + c * 8) = h;
    }
}

// -------- attention: LDS-staged KV + 4 waves/SIMD + nq=2 (R13 x R14) --------
// Block = 512 thr = 8 waves = 4 q-subgroups (32 q each) x 2 k-splits (16
// tiles each). Grid = 32 heads x 16 q-blocks (128 q) = 512 blocks, 4096
// waves = 4 waves/SIMD.
// Session ledger:
//  R10/R12: reg cap below footprint => spill catastrophe. nq=2 measured
//           VGPR=60 (R13) -> fits the 128-reg cap of 4 waves/SIMD safely.
//  R11: manual register pipeline = neutral (compiler already pipelines).
//  R13: 4 waves/SIMD but 2x global KV traffic (~20 TB/s L2 demand) = null.
//  R14: LDS-staged KV (traffic halved) but 2 waves/SIMD = null.
//  R15: setprio = -9% (starves co-wave load issue on lockstep code). Reverted.
//  R16: this kernel — bench infra died ("container failed twice"); audit
//       found no kernel-side hang (uniform barriers, legal 64KB LDS, valid
//       global_load_lds usage). Resubmitting unchanged.
//  => The one untested cell: MORE WAVES at LESS traffic. Per-wave serial
//  tile chain ~2-2.5k cyc x 2 waves ~= the observed 6.8k cyc/tile =>
//  SIMD runs at serial-chain speed; 4 waves should cut the wall.
// Staging: each ks-stream's 16 KB tile staged ONCE per block (16 x 1KB DMA
// chunks; 4 chunks per wave of that ks), double-buffered; all 4 qsub waves
// consume via linear conflict-free ds_read_b128. Global KV traffic = 256 MB
// (half of R0). LDS kv[2 ks][2 buf][K,V][4096 h] = 64 KB => 2 blocks/CU =
// 16 waves/CU. Combine scratch red[4][34][64] (34.8 KB) overlaid on kv.
// Schedule per tile: issue stage(t+1) -> ds_read+compute(t) -> syncthreads
// (vmcnt(0)+barrier drains the DMA; it was in flight under ~3k cyc compute).
// XCD swizzle (R8) kept: head = blockIdx % 32. K=32 PV (R9) kept.

__global__ __launch_bounds__(512, 4) void attn_kernel(
    const float* __restrict__ Qf,
    const _Float16* __restrict__ Kf,
    const _Float16* __restrict__ Vf,
    float* __restrict__ out) {
    __shared__ __align__(16) char smem[65536];
    // kv[ks][buf][K/V][4096 halves]
    _Float16 (*kv)[2][2][TILE_HALVES] = (_Float16 (*)[2][2][TILE_HALVES])smem;
    float (*red)[34][64] = (float (*)[34][64])smem;    // epilogue overlay [qsub]

    const int tid = threadIdx.x;
    const int wid = tid >> 6;
    const int lane = tid & 63;
    const int ln15 = lane & 15;
    const int g = lane >> 4;

    const int bh = blockIdx.x & 31;          // head-major: head h -> XCD h%8
    const int qidx = blockIdx.x >> 5;        // 16 q-blocks per head (128 q each)
    const int qsub = wid >> 1;               // q-subgroup (32 q) within block
    const int ks = wid & 1;                  // k-split half
    const int q0 = qidx * 128 + qsub * 32;
    const int t0 = ks * 16;                  // this ks-stream's 16 key tiles

    // ---- Q fragments (B-operand of 16x16x32), direct global fp32 -> f16 ----
    const float* Qg = Qf + (bh * S_LEN + q0) * DHEAD;
    half8_t qf[2][2];
#pragma unroll
    for (int nq = 0; nq < 2; ++nq)
#pragma unroll
        for (int kh = 0; kh < 2; ++kh) {
            const float4* qs = (const float4*)(Qg + (nq * 16 + ln15) * DHEAD + kh * 32 + g * 8);
            float4 a = qs[0], b = qs[1];
            qf[nq][kh] = (half8_t){(_Float16)a.x, (_Float16)a.y, (_Float16)a.z, (_Float16)a.w,
                                   (_Float16)b.x, (_Float16)b.y, (_Float16)b.z, (_Float16)b.w};
        }

    const _Float16* kb = Kf + bh * (NTILES * TILE_HALVES) + t0 * TILE_HALVES;
    const _Float16* vb = Vf + bh * (NTILES * TILE_HALVES) + t0 * TILE_HALVES;
    const int lo = lane * 8;                  // lane offset in halves (16 B)

    // staging role: this wave stages 4 of its ks-stream's 16 1-KB chunks.
    // chunk c: c<8 -> K frag c; c>=8 -> V frag c-8.
    const int c0 = qsub * 4;

    float lsum[2] = {0.f, 0.f};
    float4_t o[2][4];
#pragma unroll
    for (int nq = 0; nq < 2; ++nq)
#pragma unroll
        for (int vt = 0; vt < 4; ++vt) o[nq][vt] = (float4_t){0.f, 0.f, 0.f, 0.f};

    // ---- prologue: stage tile 0 of this ks-stream into buf 0 ----
#pragma unroll
    for (int i = 0; i < 4; ++i) {
        int c = c0 + i;
        const _Float16* gs = (c < 8 ? kb : vb) + (c & 7) * 512 + lo;
        stage16(gs, &kv[ks][0][c >> 3][(c & 7) * 512]);
    }
    __syncthreads();

#pragma unroll 2
    for (int t = 0; t < 16; ++t) {
        const int buf = t & 1;

        // issue next tile's staging into the other buffer (in flight under
        // this tile's compute; drained by the end-of-phase barrier)
        if (t < 15) {
            const int nb = (t + 1) * TILE_HALVES;
#pragma unroll
            for (int i = 0; i < 4; ++i) {
                int c = c0 + i;
                const _Float16* gs = (c < 8 ? kb : vb) + nb + (c & 7) * 512 + lo;
                stage16(gs, &kv[ks][buf ^ 1][c >> 3][(c & 7) * 512]);
            }
        }

        // ---- consume tile t from LDS (linear, conflict-free b128) ----
        const _Float16* kl = &kv[ks][buf][0][0];
        const _Float16* vl = &kv[ks][buf][1][0];

        // two 32-key chunks; per-chunk frag reads keep live regs ~70
#pragma unroll
        for (int c = 0; c < 2; ++c) {
            half8_t kA[4], vA[4];
#pragma unroll
            for (int i = 0; i < 4; ++i)
                kA[i] = *(const half8_t*)(kl + (4 * c + i) * 512 + lo);
#pragma unroll
            for (int vt = 0; vt < 4; ++vt)
                vA[vt] = *(const half8_t*)(vl + (vt * 2 + c) * 512 + lo);

            half8_t pb[2];
#pragma unroll
            for (int h = 0; h < 2; ++h) {
                half8_t a0 = kA[h * 2];
                half8_t a1 = kA[h * 2 + 1];
#pragma unroll
                for (int nq = 0; nq < 2; ++nq) {
                    float4_t s0 = (float4_t){0.f, 0.f, 0.f, 0.f};
                    s0 = __builtin_amdgcn_mfma_f32_16x16x32_f16(a0, qf[nq][0], s0, 0, 0, 0);
                    s0 = __builtin_amdgcn_mfma_f32_16x16x32_f16(a1, qf[nq][1], s0, 0, 0, 0);
                    float p0 = __builtin_amdgcn_exp2f(s0[0]);
                    float p1 = __builtin_amdgcn_exp2f(s0[1]);
                    float p2 = __builtin_amdgcn_exp2f(s0[2]);
                    float p3 = __builtin_amdgcn_exp2f(s0[3]);
                    lsum[nq] += (p0 + p1) + (p2 + p3);
                    half2_t plo = __builtin_bit_cast(half2_t, __builtin_amdgcn_cvt_pkrtz(p0, p1));
                    half2_t phi = __builtin_bit_cast(half2_t, __builtin_amdgcn_cvt_pkrtz(p2, p3));
                    pb[nq][h * 4 + 0] = plo[0];
                    pb[nq][h * 4 + 1] = plo[1];
                    pb[nq][h * 4 + 2] = phi[0];
                    pb[nq][h * 4 + 3] = phi[1];
                }
            }
            // ---- O^T += V^T . P^T over this 32-key chunk (K=32 MFMA) ----
#pragma unroll
            for (int vt = 0; vt < 4; ++vt) {
                half8_t va = vA[vt];
#pragma unroll
                for (int nq = 0; nq < 2; ++nq)
                    o[nq][vt] = __builtin_amdgcn_mfma_f32_16x16x32_f16(va, pb[nq], o[nq][vt], 0, 0, 0);
            }
        }

        __syncthreads();   // all waves done with buf; stage(t+1) drained
    }

    // ---- cross-lane l reduction (per wave, over its key half) ----
#pragma unroll
    for (int nq = 0; nq < 2; ++nq) {
        float l = lsum[nq];
        l += __shfl_xor(l, 16, 64);
        l += __shfl_xor(l, 32, 64);
        lsum[nq] = l;                       // replicated across g-groups
    }

    // ---- split-K combine via LDS overlay (kv dead after final barrier) ----
    if (ks == 1) {
#pragma unroll
        for (int nq = 0; nq < 2; ++nq)
#pragma unroll
            for (int vt = 0; vt < 4; ++vt)
#pragma unroll
                for (int r = 0; r < 4; ++r)
                    red[qsub][nq * 16 + vt * 4 + r][lane] = o[nq][vt][r];
#pragma unroll
        for (int nq = 0; nq < 2; ++nq) red[qsub][32 + nq][lane] = lsum[nq];
    }
    __syncthreads();
    if (ks == 0) {
#pragma unroll
        for (int nq = 0; nq < 2; ++nq) {
            float lt = lsum[nq] + red[qsub][32 + nq][lane];
            float inv_l = 1.0f / lt;
            int qg_global = q0 + nq * 16 + ln15;
            float* og = out + (bh * S_LEN + qg_global) * DHEAD;
#pragma unroll
            for (int vt = 0; vt < 4; ++vt) {
                float4_t vals;
#pragma unroll
                for (int r = 0; r < 4; ++r)
                    vals[r] = (o[nq][vt][r] + red[qsub][nq * 16 + vt * 4 + r][lane]) * inv_l;
                *(float4_t*)(og + vt * 16 + g * 4) = vals;
            }
        }
    }
}

// ---------------- launch ----------------

extern "C" void kernel_launch(void* const* d_in, const int* in_sizes, int n_in,
                              void* d_out, int out_size, void* d_ws, size_t ws_size,
                              hipStream_t stream) {
    const float* Kin = (const float*)d_in[0];
    const float* Qin = (const float*)d_in[1];
    const float* Vin = (const float*)d_in[2];
    float* out = (float*)d_out;

    _Float16* Kf = (_Float16*)d_ws;                 // 8 MB
    _Float16* Vf = Kf + TENS_ELEMS;                 // 8 MB

    prep_kernel<<<BHEADS * NTILES, 256, 0, stream>>>(Kin, Vin, Kf, Vf);
    attn_kernel<<<BHEADS * 16, 512, 0, stream>>>(Qin, Kf, Vf, out);
}

// Round 9
// 128.181 us; speedup vs baseline: 1.0163x; 1.0163x over previous
//
#include <hip/hip_runtime.h>

// B=2, H=16, S=2048, DK=DV=64; out flat = [B,H,S,DV] flat (raw reshape).
#define S_LEN 2048
#define DHEAD 64
#define BHEADS 32
#define NTILES 32                       // key tiles of 64
#define HEAD_ELEMS (S_LEN * DHEAD)
#define TENS_ELEMS (BHEADS * HEAD_ELEMS)
#define TILE_HALVES 4096                // 8 KB per (bh,tile) fragment block

typedef _Float16 half8_t __attribute__((ext_vector_type(8)));
typedef _Float16 half4_t __attribute__((ext_vector_type(4)));
typedef _Float16 half2_t __attribute__((ext_vector_type(2)));
typedef float float4_t __attribute__((ext_vector_type(4)));

// 1/sqrt(64) * log2(e), folded into K so scores land in exp2 domain
#define SC_LOG2E 0.18033688011112042f

// Fragment-linear layouts (16 B per lane per fragment):
//  Kf[bh][t][f=mt*2+kh][lane] : K[t*64 + mt*16 + (lane&15)][kh*32 + (lane>>4)*8 + j] * SC
//  Vf[bh][t][fv=vt*2+c][lane][j] : V[t*64 + c*32 + (j>>2)*16 + (lane>>4)*4 + (j&3)]
//                                   [vt*16 + (lane&15)]
// Key fact (R9): Vf's k-ordering equals the k-ordering of a P^T B-operand
// built by concatenating QK sub-tile outputs 2c (regs 0-3) and 2c+1 (regs
// 4-7), so PV can use mfma_f32_16x16x32_f16 directly — half the PV MFMAs.

// ---------------- prepass: build fragment-ordered K/VT ----------------
__global__ __launch_bounds__(256) void prep_kernel(const float* __restrict__ K,
                                                   const float* __restrict__ V,
                                                   _Float16* __restrict__ Kf,
                                                   _Float16* __restrict__ Vf) {
    __shared__ _Float16 tile[64][72];   // V tile [s][v], padded
    const int bh = blockIdx.x >> 5;
    const int t = blockIdx.x & 31;
    const int tid = threadIdx.x;

    const float* Ksrc = K + (bh * S_LEN + t * 64) * DHEAD;
    const float4* vs = (const float4*)(V + (bh * S_LEN + t * 64) * DHEAD);
#pragma unroll
    for (int it = 0; it < 4; ++it) {
        int i = it * 256 + tid;                 // 1024 float4 = 64x64 floats
        float4 vv = vs[i];
        int r = i >> 4, c4 = (i & 15) * 4;
        half4_t hv = {(_Float16)vv.x, (_Float16)vv.y, (_Float16)vv.z, (_Float16)vv.w};
        *(half4_t*)&tile[r][c4] = hv;
    }

    // K fragments: pure permutation of the fp32 tile, no LDS needed
    _Float16* kd = Kf + (bh * NTILES + t) * TILE_HALVES;
#pragma unroll
    for (int it = 0; it < 2; ++it) {
        int c = it * 256 + tid;                 // 512 chunks of 16 B
        int f = c >> 6, lane = c & 63;
        int row = (f >> 1) * 16 + (lane & 15);
        int d0 = (f & 1) * 32 + (lane >> 4) * 8;
        const float4* s = (const float4*)(Ksrc + row * DHEAD + d0);
        float4 a = s[0], b = s[1];
        half8_t h = {(_Float16)(a.x * SC_LOG2E), (_Float16)(a.y * SC_LOG2E),
                     (_Float16)(a.z * SC_LOG2E), (_Float16)(a.w * SC_LOG2E),
                     (_Float16)(b.x * SC_LOG2E), (_Float16)(b.y * SC_LOG2E),
                     (_Float16)(b.z * SC_LOG2E), (_Float16)(b.w * SC_LOG2E)};
        *(half8_t*)(kd + c * 8) = h;
    }
    __syncthreads();

    // VT fragments: transpose gather from LDS
    _Float16* vd = Vf + (bh * NTILES + t) * TILE_HALVES;
#pragma unroll
    for (int it = 0; it < 2; ++it) {
        int c = it * 256 + tid;
        int fv = c >> 6, lane = c & 63;
        int vt = fv >> 1, ktp = fv & 1;
        int v = vt * 16 + (lane & 15);
        int g = lane >> 4;
        half8_t h;
#pragma unroll
        for (int j = 0; j < 8; ++j) {
            int key = ktp * 32 + (j >> 2) * 16 + g * 4 + (j & 3);
            h[j] = tile[key][v];
        }
        *(half8_t*)(vd + c * 8) = h;
    }
}

// -------- attention: R0 shape + T15 chunk-interleaved pipeline --------
// Block = 4 waves = 2 q-groups (64 q) x 2 k-splits (16 tiles). Barrier-free
// main loop, global fragment loads (proven fastest sourcing).
// Session ledger:
//  R10/R12: reg cap below ~240-unified footprint => spill catastrophe.
//  R11: manual cross-tile register prefetch = neutral (compiler pipelines).
//  R13: 4 waves/SIMD + 2x traffic = null (util flat).
//  R14: LDS-staged KV @ 2 waves = null.
//  R15: setprio = -9%. R16: LDS-staged + 4 waves + nq=2 = -10% (util STILL
//       flat at 28/34 with occupancy 31%!).
//  => Utilization invariant to waves/source/traffic: the wall is the
//  per-wave serial chain QK -> (mfma latency) -> exp2/pack -> PV -> next.
// R17 (T15, proven +7-11% on MI355X attn): the tile's two 32-key chunks are
// independent. Interleave their phases so (a) QK(c1) issues under QK(c0)'s
// result latency, (b) each PV MFMA cluster runs under the OTHER chunk's
// exp2 VALU phase:
//   QK(c0,h0) QK(c1,h0) E(c0,h0) QK(c0,h1) E(c1,h0) QK(c1,h1) E(c0,h1)
//   PV(c0) E(c1,h1) PV(c1)
// Peak regs ~240 unified (kf dies before PV: compiler can pipeline next-tile
// K loads into freed regs). unroll 1: in-tile ILP replaces cross-tile
// renaming; unroll 2 would exceed the 256-reg budget.
// XCD swizzle (R8) kept. nq=4 + K=32 PV (R9) kept.

#define EXPPACK(sv, pbv, half)                                                      \
    {                                                                               \
_Pragma("unroll")                                                                   \
        for (int nq = 0; nq < 4; ++nq) {                                            \
            float p0 = __builtin_amdgcn_exp2f(sv[nq][0]);                           \
            float p1 = __builtin_amdgcn_exp2f(sv[nq][1]);                           \
            float p2 = __builtin_amdgcn_exp2f(sv[nq][2]);                           \
            float p3 = __builtin_amdgcn_exp2f(sv[nq][3]);                           \
            lsum[nq] += (p0 + p1) + (p2 + p3);                                      \
            half2_t plo = __builtin_bit_cast(half2_t, __builtin_amdgcn_cvt_pkrtz(p0, p1)); \
            half2_t phi = __builtin_bit_cast(half2_t, __builtin_amdgcn_cvt_pkrtz(p2, p3)); \
            pbv[nq][(half) * 4 + 0] = plo[0];                                       \
            pbv[nq][(half) * 4 + 1] = plo[1];                                       \
            pbv[nq][(half) * 4 + 2] = phi[0];                                       \
            pbv[nq][(half) * 4 + 3] = phi[1];                                       \
        }                                                                           \
    }

#define QK8(sv, a0, a1, init)                                                       \
    {                                                                               \
_Pragma("unroll")                                                                   \
        for (int nq = 0; nq < 4; ++nq) {                                            \
            float4_t acc = (float4_t){0.f, 0.f, 0.f, 0.f};                          \
            acc = __builtin_amdgcn_mfma_f32_16x16x32_f16(a0, qf[nq][0], acc, 0, 0, 0); \
            acc = __builtin_amdgcn_mfma_f32_16x16x32_f16(a1, qf[nq][1], acc, 0, 0, 0); \
            sv[nq] = acc;                                                           \
        }                                                                           \
    }

__global__ __launch_bounds__(256, 2) void attn_kernel(
    const float* __restrict__ Qf,
    const _Float16* __restrict__ Kf,
    const _Float16* __restrict__ Vf,
    float* __restrict__ out) {
    __shared__ float red[2][68][64];    // [qg][64 o-floats + 4 lsum][lane]

    const int tid = threadIdx.x;
    const int wid = tid >> 6;
    const int lane = tid & 63;
    const int ln15 = lane & 15;
    const int g = lane >> 4;

    const int bh = blockIdx.x & 31;          // head-major: head h -> XCD h%8
    const int qidx = blockIdx.x >> 5;        // 16 q-blocks per head (128 q each)
    const int qg = wid >> 1;                 // q-group within block
    const int ks = wid & 1;                  // k-split half
    const int q0 = qidx * 128 + qg * 64;
    const int t0 = ks * 16;                  // this wave's 16 key tiles

    // ---- Q fragments (B-operand of 16x16x32), direct global fp32 -> f16 ----
    const float* Qg = Qf + (bh * S_LEN + q0) * DHEAD;
    half8_t qf[4][2];
#pragma unroll
    for (int nq = 0; nq < 4; ++nq)
#pragma unroll
        for (int kh = 0; kh < 2; ++kh) {
            const float4* qs = (const float4*)(Qg + (nq * 16 + ln15) * DHEAD + kh * 32 + g * 8);
            float4 a = qs[0], b = qs[1];
            qf[nq][kh] = (half8_t){(_Float16)a.x, (_Float16)a.y, (_Float16)a.z, (_Float16)a.w,
                                   (_Float16)b.x, (_Float16)b.y, (_Float16)b.z, (_Float16)b.w};
        }

    const _Float16* kb = Kf + bh * (NTILES * TILE_HALVES) + t0 * TILE_HALVES;
    const _Float16* vb = Vf + bh * (NTILES * TILE_HALVES) + t0 * TILE_HALVES;
    const int lo = lane * 8;                  // lane offset in halves

    float lsum[4] = {0.f, 0.f, 0.f, 0.f};
    float4_t o[4][4];
#pragma unroll
    for (int nq = 0; nq < 4; ++nq)
#pragma unroll
        for (int vt = 0; vt < 4; ++vt) o[nq][vt] = (float4_t){0.f, 0.f, 0.f, 0.f};

#pragma unroll 1
    for (int t = 0; t < 16; ++t) {
        const int base = t * TILE_HALVES;
        half8_t kf[8], vf[8];
#pragma unroll
        for (int f = 0; f < 8; ++f) kf[f] = *(const half8_t*)(kb + base + f * 512 + lo);
#pragma unroll
        for (int f = 0; f < 8; ++f) vf[f] = *(const half8_t*)(vb + base + f * 512 + lo);

        float4_t s0[4], s1[4];              // QK accumulators: chunk0 / chunk1
        half8_t pb0[4], pb1[4];             // packed P operands

        // ---- interleaved schedule (chunks c0/c1 are independent) ----
        QK8(s0, kf[0], kf[1], 0);           // QK(c0,h0)  [mt=0]
        QK8(s1, kf[4], kf[5], 0);           // QK(c1,h0)  [mt=2] — hides s0 latency
        EXPPACK(s0, pb0, 0);                // exp2(c0,h0): s0 long ready
        QK8(s0, kf[2], kf[3], 0);           // QK(c0,h1)  [mt=1]
        EXPPACK(s1, pb1, 0);                // exp2(c1,h0) under QK(c0,h1) drain
        QK8(s1, kf[6], kf[7], 0);           // QK(c1,h1)  [mt=3]
        EXPPACK(s0, pb0, 1);                // pb0 complete
        // ---- PV(c0): MFMA cluster overlapped by next exp2 phase ----
#pragma unroll
        for (int vt = 0; vt < 4; ++vt) {
            half8_t va = vf[vt * 2 + 0];
#pragma unroll
            for (int nq = 0; nq < 4; ++nq)
                o[nq][vt] = __builtin_amdgcn_mfma_f32_16x16x32_f16(va, pb0[nq], o[nq][vt], 0, 0, 0);
        }
        EXPPACK(s1, pb1, 1);                // exp2(c1,h1) ∥ PV(c0) drain
        // ---- PV(c1) ----
#pragma unroll
        for (int vt = 0; vt < 4; ++vt) {
            half8_t va = vf[vt * 2 + 1];
#pragma unroll
            for (int nq = 0; nq < 4; ++nq)
                o[nq][vt] = __builtin_amdgcn_mfma_f32_16x16x32_f16(va, pb1[nq], o[nq][vt], 0, 0, 0);
        }
    }

    // ---- cross-lane l reduction (per wave, over its key half) ----
#pragma unroll
    for (int nq = 0; nq < 4; ++nq) {
        float l = lsum[nq];
        l += __shfl_xor(l, 16, 64);
        l += __shfl_xor(l, 32, 64);
        lsum[nq] = l;                       // replicated across g-groups
    }

    // ---- split-K combine via LDS (conflict-free column layout) ----
    if (ks == 1) {
#pragma unroll
        for (int nq = 0; nq < 4; ++nq)
#pragma unroll
            for (int vt = 0; vt < 4; ++vt)
#pragma unroll
                for (int r = 0; r < 4; ++r)
                    red[qg][nq * 16 + vt * 4 + r][lane] = o[nq][vt][r];
#pragma unroll
        for (int nq = 0; nq < 4; ++nq) red[qg][64 + nq][lane] = lsum[nq];
    }
    __syncthreads();
    if (ks == 0) {
#pragma unroll
        for (int nq = 0; nq < 4; ++nq) {
            float lt = lsum[nq] + red[qg][64 + nq][lane];
            float inv_l = 1.0f / lt;
            int qg_global = q0 + nq * 16 + ln15;
            float* og = out + (bh * S_LEN + qg_global) * DHEAD;
#pragma unroll
            for (int vt = 0; vt < 4; ++vt) {
                float4_t vals;
#pragma unroll
                for (int r = 0; r < 4; ++r)
                    vals[r] = (o[nq][vt][r] + red[qg][nq * 16 + vt * 4 + r][lane]) * inv_l;
                *(float4_t*)(og + vt * 16 + g * 4) = vals;
            }
        }
    }
}

// ---------------- launch ----------------

extern "C" void kernel_launch(void* const* d_in, const int* in_sizes, int n_in,
                              void* d_out, int out_size, void* d_ws, size_t ws_size,
                              hipStream_t stream) {
    const float* Kin = (const float*)d_in[0];
    const float* Qin = (const float*)d_in[1];
    const float* Vin = (const float*)d_in[2];
    float* out = (float*)d_out;

    _Float16* Kf = (_Float16*)d_ws;                 // 8 MB
    _Float16* Vf = Kf + TENS_ELEMS;                 // 8 MB

    prep_kernel<<<BHEADS * NTILES, 256, 0, stream>>>(Kin, Vin, Kf, Vf);
    attn_kernel<<<BHEADS * 16, 256, 0, stream>>>(Qin, Kf, Vf, out);
}

// Round 10
// 126.020 us; speedup vs baseline: 1.0337x; 1.0171x over previous
//
#include <hip/hip_runtime.h>

// B=2, H=16, S=2048, DK=DV=64; out flat = [B,H,S,DV] flat (raw reshape).
#define S_LEN 2048
#define DHEAD 64
#define BHEADS 32
#define NTILES 32                       // key tiles of 64
#define HEAD_ELEMS (S_LEN * DHEAD)
#define TENS_ELEMS (BHEADS * HEAD_ELEMS)
#define TILE_HALVES 4096                // 8 KB per (bh,tile) fragment block

typedef _Float16 half8_t __attribute__((ext_vector_type(8)));
typedef _Float16 half4_t __attribute__((ext_vector_type(4)));
typedef _Float16 half2_t __attribute__((ext_vector_type(2)));
typedef float float4_t __attribute__((ext_vector_type(4)));

// 1/sqrt(64) * log2(e), folded into K so scores land in exp2 domain
#define SC_LOG2E 0.18033688011112042f

// Fragment-linear layouts (16 B per lane per fragment):
//  Kf[bh][t][f=mt*2+kh][lane] : K[t*64 + mt*16 + (lane&15)][kh*32 + (lane>>4)*8 + j] * SC
//  Vf[bh][t][fv=vt*2+c][lane][j] : V[t*64 + c*32 + (j>>2)*16 + (lane>>4)*4 + (j&3)]
//                                   [vt*16 + (lane&15)]
// Key fact (R9): Vf's k-ordering equals the k-ordering of a P^T B-operand
// built by concatenating QK sub-tile outputs 2c (regs 0-3) and 2c+1 (regs
// 4-7), so PV can use mfma_f32_16x16x32_f16 directly — half the PV MFMAs.

// ---------------- prepass: build fragment-ordered K/VT ----------------
__global__ __launch_bounds__(256) void prep_kernel(const float* __restrict__ K,
                                                   const float* __restrict__ V,
                                                   _Float16* __restrict__ Kf,
                                                   _Float16* __restrict__ Vf) {
    __shared__ _Float16 tile[64][72];   // V tile [s][v], padded
    const int bh = blockIdx.x >> 5;
    const int t = blockIdx.x & 31;
    const int tid = threadIdx.x;

    const float* Ksrc = K + (bh * S_LEN + t * 64) * DHEAD;
    const float4* vs = (const float4*)(V + (bh * S_LEN + t * 64) * DHEAD);
#pragma unroll
    for (int it = 0; it < 4; ++it) {
        int i = it * 256 + tid;                 // 1024 float4 = 64x64 floats
        float4 vv = vs[i];
        int r = i >> 4, c4 = (i & 15) * 4;
        half4_t hv = {(_Float16)vv.x, (_Float16)vv.y, (_Float16)vv.z, (_Float16)vv.w};
        *(half4_t*)&tile[r][c4] = hv;
    }

    // K fragments: pure permutation of the fp32 tile, no LDS needed
    _Float16* kd = Kf + (bh * NTILES + t) * TILE_HALVES;
#pragma unroll
    for (int it = 0; it < 2; ++it) {
        int c = it * 256 + tid;                 // 512 chunks of 16 B
        int f = c >> 6, lane = c & 63;
        int row = (f >> 1) * 16 + (lane & 15);
        int d0 = (f & 1) * 32 + (lane >> 4) * 8;
        const float4* s = (const float4*)(Ksrc + row * DHEAD + d0);
        float4 a = s[0], b = s[1];
        half8_t h = {(_Float16)(a.x * SC_LOG2E), (_Float16)(a.y * SC_LOG2E),
                     (_Float16)(a.z * SC_LOG2E), (_Float16)(a.w * SC_LOG2E),
                     (_Float16)(b.x * SC_LOG2E), (_Float16)(b.y * SC_LOG2E),
                     (_Float16)(b.z * SC_LOG2E), (_Float16)(b.w * SC_LOG2E)};
        *(half8_t*)(kd + c * 8) = h;
    }
    __syncthreads();

    // VT fragments: transpose gather from LDS
    _Float16* vd = Vf + (bh * NTILES + t) * TILE_HALVES;
#pragma unroll
    for (int it = 0; it < 2; ++it) {
        int c = it * 256 + tid;
        int fv = c >> 6, lane = c & 63;
        int vt = fv >> 1, ktp = fv & 1;
        int v = vt * 16 + (lane & 15);
        int g = lane >> 4;
        half8_t h;
#pragma unroll
        for (int j = 0; j < 8; ++j) {
            int key = ktp * 32 + (j >> 2) * 16 + g * 4 + (j & 3);
            h[j] = tile[key][v];
        }
        *(half8_t*)(vd + c * 8) = h;
    }
}

// -------- attention: R0 structure + lsum via ones-MFMA (VALU work deletion) --------
// Block = 4 waves = 2 q-groups (64 queries each) x 2 k-splits (16 tiles each).
// Session ledger (all measured on MI355X):
//  R10/R12: reg cap below ~192-240 unified footprint => spill catastrophe.
//  R11: manual register prefetch = neutral (compiler already pipelines).
//  R13: 4 waves/SIMD + 2x traffic = null. R14: LDS-staged KV = null.
//  R15: setprio = -9%. R16: LDS + 4 waves + nq=2 = -10% (util flat at 28/34
//       even at occupancy 31%). R17: chunk-interleaved ILP schedule = null.
//  => MfmaUtil/VALUBusy invariant to occupancy, traffic, sourcing, schedule.
//  Remaining honest lever: delete work from the busier pipe (VALU).
// R18: the lsum row-sum (48 v_add/tile, ~18% of VALU work) is matmul-shaped:
// an extra PV MFMA with all-ones A-operand computes o4[nq][*] = sum_k P[k][q]
// (replicated over regs and g-groups by the D-layout) on the MFMA pipe.
// Also deletes the shfl_xor k-group reduction epilogue and shortens the
// exp2->cvt dependency chain. +8 MFMA/tile (~39 cyc on the 28% pipe),
// +20 VGPR (~192 unified total, fits 2-wave budget).
// XCD swizzle (R8) kept. nq=4 + K=32 PV (R9) kept.

__global__ __launch_bounds__(256, 2) void attn_kernel(
    const float* __restrict__ Qf,
    const _Float16* __restrict__ Kf,
    const _Float16* __restrict__ Vf,
    float* __restrict__ out) {
    __shared__ float red[2][68][64];    // [qg][64 o-floats + 4 lsum][lane]

    const int tid = threadIdx.x;
    const int wid = tid >> 6;
    const int lane = tid & 63;
    const int ln15 = lane & 15;
    const int g = lane >> 4;

    const int bh = blockIdx.x & 31;          // head-major: head h -> XCD h%8
    const int qidx = blockIdx.x >> 5;        // 16 q-blocks per head (128 q each)
    const int qg = wid >> 1;                 // q-group within block
    const int ks = wid & 1;                  // k-split half
    const int q0 = qidx * 128 + qg * 64;
    const int t0 = ks * 16;                  // this wave's 16 key tiles

    // ---- Q fragments (B-operand of 16x16x32), direct global fp32 -> f16 ----
    const float* Qg = Qf + (bh * S_LEN + q0) * DHEAD;
    half8_t qf[4][2];
#pragma unroll
    for (int nq = 0; nq < 4; ++nq)
#pragma unroll
        for (int kh = 0; kh < 2; ++kh) {
            const float4* qs = (const float4*)(Qg + (nq * 16 + ln15) * DHEAD + kh * 32 + g * 8);
            float4 a = qs[0], b = qs[1];
            qf[nq][kh] = (half8_t){(_Float16)a.x, (_Float16)a.y, (_Float16)a.z, (_Float16)a.w,
                                   (_Float16)b.x, (_Float16)b.y, (_Float16)b.z, (_Float16)b.w};
        }

    const _Float16* kb = Kf + bh * (NTILES * TILE_HALVES) + t0 * TILE_HALVES;
    const _Float16* vb = Vf + bh * (NTILES * TILE_HALVES) + t0 * TILE_HALVES;
    const int lo = lane * 8;                  // lane offset in halves

    const half8_t vones = {(_Float16)1.f, (_Float16)1.f, (_Float16)1.f, (_Float16)1.f,
                           (_Float16)1.f, (_Float16)1.f, (_Float16)1.f, (_Float16)1.f};

    float4_t o[4][4];
    float4_t o4[4];                     // row-sum accumulators (ones-MFMA)
#pragma unroll
    for (int nq = 0; nq < 4; ++nq) {
#pragma unroll
        for (int vt = 0; vt < 4; ++vt) o[nq][vt] = (float4_t){0.f, 0.f, 0.f, 0.f};
        o4[nq] = (float4_t){0.f, 0.f, 0.f, 0.f};
    }

#pragma unroll 2
    for (int t = 0; t < 16; ++t) {
        const int base = t * TILE_HALVES;
        half8_t kf[8], vf[8];
#pragma unroll
        for (int f = 0; f < 8; ++f) kf[f] = *(const half8_t*)(kb + base + f * 512 + lo);
#pragma unroll
        for (int f = 0; f < 8; ++f) vf[f] = *(const half8_t*)(vb + base + f * 512 + lo);

        // two 32-key chunks; QK -> exp2 -> PV (K=32) per chunk
#pragma unroll
        for (int c = 0; c < 2; ++c) {
            half8_t pb[4];
#pragma unroll
            for (int h = 0; h < 2; ++h) {
                const int mt = 2 * c + h;
                half8_t a0 = kf[mt * 2];
                half8_t a1 = kf[mt * 2 + 1];
#pragma unroll
                for (int nq = 0; nq < 4; ++nq) {
                    float4_t c0 = (float4_t){0.f, 0.f, 0.f, 0.f};
                    c0 = __builtin_amdgcn_mfma_f32_16x16x32_f16(a0, qf[nq][0], c0, 0, 0, 0);
                    c0 = __builtin_amdgcn_mfma_f32_16x16x32_f16(a1, qf[nq][1], c0, 0, 0, 0);
                    float p0 = __builtin_amdgcn_exp2f(c0[0]);
                    float p1 = __builtin_amdgcn_exp2f(c0[1]);
                    float p2 = __builtin_amdgcn_exp2f(c0[2]);
                    float p3 = __builtin_amdgcn_exp2f(c0[3]);
                    half2_t plo = __builtin_bit_cast(half2_t, __builtin_amdgcn_cvt_pkrtz(p0, p1));
                    half2_t phi = __builtin_bit_cast(half2_t, __builtin_amdgcn_cvt_pkrtz(p2, p3));
                    pb[nq][h * 4 + 0] = plo[0];
                    pb[nq][h * 4 + 1] = plo[1];
                    pb[nq][h * 4 + 2] = phi[0];
                    pb[nq][h * 4 + 3] = phi[1];
                }
            }
            // ---- O^T += V^T . P^T over this 32-key chunk (K=32 MFMA) ----
#pragma unroll
            for (int vt = 0; vt < 4; ++vt) {
                half8_t va = vf[vt * 2 + c];
#pragma unroll
                for (int nq = 0; nq < 4; ++nq)
                    o[nq][vt] = __builtin_amdgcn_mfma_f32_16x16x32_f16(va, pb[nq], o[nq][vt], 0, 0, 0);
            }
            // ---- lsum via ones-MFMA: o4[nq][*] += sum_k P^T[k][q] ----
#pragma unroll
            for (int nq = 0; nq < 4; ++nq)
                o4[nq] = __builtin_amdgcn_mfma_f32_16x16x32_f16(vones, pb[nq], o4[nq], 0, 0, 0);
        }
    }

    // lsum[nq] = o4[nq][0]: D[v][q] is v-independent => replicated over regs
    // AND g-groups already (no cross-lane reduction needed).
    float lsum[4];
#pragma unroll
    for (int nq = 0; nq < 4; ++nq) lsum[nq] = o4[nq][0];

    // ---- split-K combine via LDS (conflict-free column layout) ----
    if (ks == 1) {
#pragma unroll
        for (int nq = 0; nq < 4; ++nq)
#pragma unroll
            for (int vt = 0; vt < 4; ++vt)
#pragma unroll
                for (int r = 0; r < 4; ++r)
                    red[qg][nq * 16 + vt * 4 + r][lane] = o[nq][vt][r];
#pragma unroll
        for (int nq = 0; nq < 4; ++nq) red[qg][64 + nq][lane] = lsum[nq];
    }
    __syncthreads();
    if (ks == 0) {
#pragma unroll
        for (int nq = 0; nq < 4; ++nq) {
            float lt = lsum[nq] + red[qg][64 + nq][lane];
            float inv_l = 1.0f / lt;
            int qg_global = q0 + nq * 16 + ln15;
            float* og = out + (bh * S_LEN + qg_global) * DHEAD;
#pragma unroll
            for (int vt = 0; vt < 4; ++vt) {
                float4_t vals;
#pragma unroll
                for (int r = 0; r < 4; ++r)
                    vals[r] = (o[nq][vt][r] + red[qg][nq * 16 + vt * 4 + r][lane]) * inv_l;
                *(float4_t*)(og + vt * 16 + g * 4) = vals;
            }
        }
    }
}

// ---------------- launch ----------------

extern "C" void kernel_launch(void* const* d_in, const int* in_sizes, int n_in,
                              void* d_out, int out_size, void* d_ws, size_t ws_size,
                              hipStream_t stream) {
    const float* Kin = (const float*)d_in[0];
    const float* Qin = (const float*)d_in[1];
    const float* Vin = (const float*)d_in[2];
    float* out = (float*)d_out;

    _Float16* Kf = (_Float16*)d_ws;                 // 8 MB
    _Float16* Vf = Kf + TENS_ELEMS;                 // 8 MB

    prep_kernel<<<BHEADS * NTILES, 256, 0, stream>>>(Kin, Vin, Kf, Vf);
    attn_kernel<<<BHEADS * 16, 256, 0, stream>>>(Qin, Kf, Vf, out);
}